// Round 9
// baseline (162.702 us; speedup 1.0000x reference)
//
#include <hip/hip_runtime.h>

#define T_STEPS 256
#define IMG 512
#define HW (IMG * IMG)
#define TW 64                  // tile width (per wave)
#define TH 8                   // tile height
#define ROWCHK 18              // real 16B chunks per halo row (cols -4..67)
#define ROWSTRIDE 21           // LDS slot stride per halo row (gcd(21*4,32)=4 dwords -> uniform banks)
#define HTH 12                 // halo rows -2..9
#define FRAME_DW 1024          // 256 slots * 4 dwords = 4 KiB per frame
#define NFR 4                  // ring frames per wave  (4 waves*4*4KiB = 64 KiB)
#define WARM 32                // warm-up steps (0.8^32 * 46 ~ 0.04 << threshold)

// Zero page for dummy/OOB chunks (device global: never written, stays 0).
__device__ __align__(16) float g_zeropage[8] = {0, 0, 0, 0, 0, 0, 0, 0};

typedef const __attribute__((address_space(1))) unsigned int* gptr_t;
typedef __attribute__((address_space(3))) unsigned int* lptr_t;
typedef float vf4 __attribute__((ext_vector_type(4)));

// out[t] = 0.8*out[t-1] + conv(x)[t-1]; out[0]=0 — conv and LI scan commute.
// 4 waves/block, each wave owns the SAME 64x8 tile but a DIFFERENT t-segment
// (t in [64w-32, 64w+64), writing from 64w; 32-step S=0 warm-up, decay 0.8^32
// makes the splice error ~0.04). Waves are fully independent: disjoint LDS
// rings, per-wave counted vmcnt, NO barriers. 2 blocks/CU -> 2 waves/SIMD.
__launch_bounds__(256)
__global__ void conv_li_kernel(const float* __restrict__ x,
                               const float* __restrict__ kern,
                               float* __restrict__ out) {
    __shared__ __align__(16) float lds[4][NFR][FRAME_DW];
    const int lane = threadIdx.x;
    const int w = threadIdx.y;     // wave id = t-segment
    const int bid = blockIdx.x;
    // 512 blocks over 8 XCDs (bijective): XCD k owns an 8-tile-row band.
    const int vbid = (bid & 7) * 64 + (bid >> 3);
    const int bx = vbid & 7;       // 8 tiles across
    const int by = vbid >> 3;      // 64 tile rows

    // 5x5 kernel -> wave-uniform (SGPR) weights.
    float kw[25];
#pragma unroll
    for (int i = 0; i < 25; ++i)
        kw[i] = __int_as_float(__builtin_amdgcn_readfirstlane(__float_as_int(kern[i])));

    // Staging: issue k stages LDS slots k*64..k*64+63; lane handles slot
    // s = k*64+lane -> halo row s/21, chunk col s%21 (cc<18 real, else dummy).
    const float* src[4]; bool ok[4];
#pragma unroll
    for (int k = 0; k < 4; ++k) {
        int s = k * 64 + lane;
        int row = s / ROWSTRIDE, cc = s - row * ROWSTRIDE;
        int gy = by * TH + row - 2;
        int gx = bx * TW + cc * 4 - 4;
        ok[k] = (row < HTH) && (cc < ROWCHK) &&
                (gy >= 0) && (gy < IMG) && (gx >= 0) && (gx <= IMG - 4);
        src[k] = x + (size_t)(ok[k] ? gy : 0) * IMG + (ok[k] ? gx : 0);
    }

    auto GLDS = [&](int fi, int tf) {          // one frame = 4 glds issues
        float* fb = &lds[w][fi][0];
#pragma unroll
        for (int k = 0; k < 4; ++k) {
            const float* p = ok[k] ? src[k] + (size_t)tf * HW : g_zeropage;
            __builtin_amdgcn_global_load_lds((gptr_t)p, (lptr_t)(fb + k * 256), 16, 0, 0);
        }
    };

    const int q = lane & 7;        // col-octet (8 out cols)
    const int rr = lane >> 3;      // out row within tile
    const size_t obase = (size_t)(by * TH + rr) * IMG + bx * TW + q * 8;

    float st[8] = {0.f, 0.f, 0.f, 0.f, 0.f, 0.f, 0.f, 0.f};

    auto STEP = [&](int fi, int t, bool dostore) {
        float acc[8] = {0.f, 0.f, 0.f, 0.f, 0.f, 0.f, 0.f, 0.f};
        const float* F = &lds[w][fi][0];
        // w16[i] = col 8q-4+i of halo row rr+dy; outputs use w16[2..13].
#pragma unroll
        for (int dy = 0; dy < 5; ++dy) {
            const float* L = F + ((rr + dy) * ROWSTRIDE + 2 * q) * 4;
            vf4 c0 = *(const vf4*)(L);
            vf4 c1 = *(const vf4*)(L + 4);
            vf4 c2 = *(const vf4*)(L + 8);
            vf4 c3 = *(const vf4*)(L + 12);
            const float w16[16] = {c0.x, c0.y, c0.z, c0.w, c1.x, c1.y, c1.z, c1.w,
                                   c2.x, c2.y, c2.z, c2.w, c3.x, c3.y, c3.z, c3.w};
            const float k0 = kw[dy * 5 + 0], k1 = kw[dy * 5 + 1], k2 = kw[dy * 5 + 2];
            const float k3 = kw[dy * 5 + 3], k4 = kw[dy * 5 + 4];
#pragma unroll
            for (int o = 0; o < 8; ++o) {
                acc[o] = fmaf(k0, w16[o + 2], acc[o]);
                acc[o] = fmaf(k1, w16[o + 3], acc[o]);
                acc[o] = fmaf(k2, w16[o + 4], acc[o]);
                acc[o] = fmaf(k3, w16[o + 5], acc[o]);
                acc[o] = fmaf(k4, w16[o + 6], acc[o]);
            }
        }
        if (dostore) {                         // plain stores: contiguous-merge in L2
            vf4 lo = {st[0], st[1], st[2], st[3]};
            vf4 hi = {st[4], st[5], st[6], st[7]};
            float* op = out + (size_t)t * HW + obase;
            *(vf4*)op = lo;                    // out[t] = S_{t-1}
            *(vf4*)(op + 4) = hi;
        }
#pragma unroll
        for (int o = 0; o < 8; ++o)
            st[o] = st[o] - 0.2f * st[o] + acc[o];       // S_t = 0.8*S + y[t]
    };

    // Segment: compute from tc0, store from 64w. Groups of 2 steps.
    const int tc0 = (w == 0) ? 0 : (w * 64 - WARM);
    const int WG = (w == 0) ? 0 : (WARM / 2);  // warm groups
    const int NG = WG + 32;                    // total groups (64 write steps)

    // Prologue: frames 0..3 <- tc0..tc0+3 (16 glds; batches of 2 frames = 8).
    GLDS(0, tc0); GLDS(1, tc0 + 1); GLDS(2, tc0 + 2); GLDS(3, tc0 + 3);

#define GROUP(G, DS_)                                         \
    do {                                                      \
        int fa_ = (2 * (G)) & 3;                              \
        int tg_ = tc0 + 2 * (G);                              \
        STEP(fa_, tg_, DS_);                                  \
        STEP(fa_ + 1, tg_ + 1, DS_);                          \
        int p0_ = tg_ + 4 > 255 ? 255 : tg_ + 4;              \
        int p1_ = tg_ + 5 > 255 ? 255 : tg_ + 5;              \
        GLDS(fa_, p0_); GLDS(fa_ + 1, p1_);                   \
    } while (0)

    // Groups 0..WG: previous group had no stores -> newer = next batch only.
#pragma clang loop unroll(disable)
    for (int g = 0; g <= WG; ++g) {
        asm volatile("s_waitcnt vmcnt(8)" ::: "memory");
        GROUP(g, g >= WG);
    }
    // Steady state: newer = stores(4) + next batch(8) = 12 (never waits stores).
#pragma clang loop unroll(disable)
    for (int g = WG + 1; g < NG; ++g) {
        asm volatile("s_waitcnt vmcnt(12)" ::: "memory");
        GROUP(g, true);
    }
#undef GROUP
}

extern "C" void kernel_launch(void* const* d_in, const int* in_sizes, int n_in,
                              void* d_out, int out_size, void* d_ws, size_t ws_size,
                              hipStream_t stream) {
    const float* x = (const float*)d_in[0];      // [256,1,512,512] f32
    const float* kern = (const float*)d_in[1];   // [5,5] f32
    float* out = (float*)d_out;                  // [256,1,512,512] f32

    conv_li_kernel<<<dim3(512), dim3(64, 4), 0, stream>>>(x, kern, out);
}

// Round 10
// 127.570 us; speedup vs baseline: 1.2754x; 1.2754x over previous
//
#include <hip/hip_runtime.h>

#define T_STEPS 256
#define IMG 512
#define HW (IMG * IMG)
#define TW 32
#define TH 8
#define HTW 40                 // dwords per halo row (cols -4..35) = 10 chunks
#define HTH 12                 // halo rows -2..9
#define NCHK 120               // real 16B chunks per frame
#define BUF_DW 512             // 128 chunks (8 dummy) * 4 dwords per frame buffer
#define NBUF 12                // ring of 12 frame buffers = 24 KiB LDS

// Zero page for fully-OOB halo chunks (device global: never written, stays 0).
__device__ __align__(16) float g_zeropage[8] = {0, 0, 0, 0, 0, 0, 0, 0};

typedef const __attribute__((address_space(1))) unsigned int* gptr_t;
typedef __attribute__((address_space(3))) unsigned int* lptr_t;
typedef float vf4 __attribute__((ext_vector_type(4)));

// out[t] = 0.8*out[t-1] + conv(x)[t-1]; out[0]=0 — conv and LI scan commute.
// Single-wave blocks, no barriers. global_load_lds staging, ring-12 buffers,
// groups of 4 steps per counted vmcnt (stores always newer than the waited
// glds batch -> never store-stalled). Reads per halo row are b64+b128+b64
// (exact 8-dword window, ~24 LDS-pipe cyc/row vs 36 for 3xb128).
__launch_bounds__(64)
__global__ void conv_li_kernel(const float* __restrict__ x,
                               const float* __restrict__ kern,
                               float* __restrict__ out) {
    __shared__ __align__(16) float lds[NBUF][BUF_DW];
    const int tid = threadIdx.x;
    const int bid = blockIdx.x;
    // 1024 blocks over 8 XCDs (bijective): vertical halo sharing stays per-XCD L2.
    const int vbid = (bid & 7) * 128 + (bid >> 3);
    const int bx = vbid & 15;      // 16 tiles across
    const int by = vbid >> 4;      // 64 tile rows

    // 5x5 kernel -> wave-uniform (SGPR) weights.
    float kw[25];
#pragma unroll
    for (int i = 0; i < 25; ++i)
        kw[i] = __int_as_float(__builtin_amdgcn_readfirstlane(__float_as_int(kern[i])));

    // DMA source chunks: lane stages chunk tid (issue A) and tid+64 (issue B).
    // Chunk c -> halo row c/10, col-chunk c%10; every chunk is fully in-image
    // or fully out (-> zero page). gx is 16B-aligned.
    const float* srcA; const float* srcB; bool okA, okB;
    {
        int c = tid;
        int row = c / 10, cc = c - row * 10;
        int gy = by * TH + row - 2, gx = bx * TW + cc * 4 - 4;
        okA = (gy >= 0) && (gy < IMG) && (gx >= 0) && (gx <= IMG - 4);
        srcA = x + (size_t)(okA ? gy : 0) * IMG + (okA ? gx : 0);
        c = tid + 64;
        row = c / 10; cc = c - row * 10;
        gy = by * TH + row - 2; gx = bx * TW + cc * 4 - 4;
        okB = (c < NCHK) && (gy >= 0) && (gy < IMG) && (gx >= 0) && (gx <= IMG - 4);
        srcB = x + (size_t)(okB ? gy : 0) * IMG + (okB ? gx : 0);
    }

    auto GLDS = [&](int bi, int tf) {
        const float* pA = okA ? srcA + (size_t)tf * HW : g_zeropage;
        const float* pB = okB ? srcB + (size_t)tf * HW : g_zeropage;
        __builtin_amdgcn_global_load_lds((gptr_t)pA, (lptr_t)&lds[bi][0], 16, 0, 0);
        __builtin_amdgcn_global_load_lds((gptr_t)pB, (lptr_t)&lds[bi][256], 16, 0, 0);
    };
    auto BATCH = [&](int bufbase, int f0) {   // 4 frames = 8 glds, issued in order
#pragma unroll
        for (int j = 0; j < 4; ++j) {
            int tf = f0 + j; if (tf > T_STEPS - 1) tf = T_STEPS - 1;
            GLDS(bufbase + j, tf);
        }
    };

    const int q = tid & 7;         // col-quad (4 out cols)
    const int rr = tid >> 3;       // out row within tile
    const size_t obase = (size_t)(by * TH + rr) * IMG + bx * TW + q * 4;

    vf4 st = {0.f, 0.f, 0.f, 0.f};

    auto STEP = [&](int bi, int t) {
        float ax = 0.f, ay = 0.f, az = 0.f, aw = 0.f;
        // Halo row h = rr+dy starts at dword h*40. Window cols 4q-2..4q+5 =
        // dwords h*40 + 4q+2 .. 4q+9: b64 + b128 + b64, all aligned.
        const float* Bp = &lds[bi][rr * HTW + q * 4];
#pragma unroll
        for (int dy = 0; dy < 5; ++dy) {
            const float* L = Bp + dy * HTW;
            float2 lo = *(const float2*)(L + 2);   // cols 4q-2, 4q-1
            vf4 md = *(const vf4*)(L + 4);         // cols 4q .. 4q+3
            float2 hi = *(const float2*)(L + 8);   // cols 4q+4, 4q+5
            const float e0 = lo.x, e1 = lo.y, e2 = md.x, e3 = md.y;
            const float e4 = md.z, e5 = md.w, e6 = hi.x, e7 = hi.y;
            const float k0 = kw[dy * 5 + 0], k1 = kw[dy * 5 + 1], k2 = kw[dy * 5 + 2];
            const float k3 = kw[dy * 5 + 3], k4 = kw[dy * 5 + 4];
            ax = fmaf(k0, e0, ax); ax = fmaf(k1, e1, ax); ax = fmaf(k2, e2, ax);
            ax = fmaf(k3, e3, ax); ax = fmaf(k4, e4, ax);
            ay = fmaf(k0, e1, ay); ay = fmaf(k1, e2, ay); ay = fmaf(k2, e3, ay);
            ay = fmaf(k3, e4, ay); ay = fmaf(k4, e5, ay);
            az = fmaf(k0, e2, az); az = fmaf(k1, e3, az); az = fmaf(k2, e4, az);
            az = fmaf(k3, e5, az); az = fmaf(k4, e6, az);
            aw = fmaf(k0, e3, aw); aw = fmaf(k1, e4, aw); aw = fmaf(k2, e5, aw);
            aw = fmaf(k3, e6, aw); aw = fmaf(k4, e7, aw);
        }
        vf4 s = st;
        __builtin_nontemporal_store(s, (vf4*)(out + (size_t)t * HW + obase));
        st.x = st.x - 0.2f * st.x + ax;      // S_t = 0.8*S_{t-1} + y[t]
        st.y = st.y - 0.2f * st.y + ay;
        st.z = st.z - 0.2f * st.z + az;
        st.w = st.w - 0.2f * st.w + aw;
    };

    // Prologue: frames 0..7 in flight (16 glds).
    BATCH(0, 0);
    BATCH(4, 4);

    // Group 0 (frames 0..3): outstanding 16, need oldest 8 -> vmcnt(8).
    asm volatile("s_waitcnt vmcnt(8)" ::: "memory");
    STEP(0, 0); STEP(1, 1); STEP(2, 2); STEP(3, 3);
    BATCH(8, 8);

    // Steady state: at group top, outstanding = batch(this:8) + stores(4) +
    // batch(next:8) = 20; waited batch is oldest -> vmcnt(12) never touches
    // stores. 21 super-groups x 12 steps = t 4..255.
#pragma clang loop unroll(disable)
    for (int sg = 0; sg < 21; ++sg) {
        const int t0 = 4 + sg * 12;
        asm volatile("s_waitcnt vmcnt(12)" ::: "memory");
        STEP(4, t0 + 0); STEP(5, t0 + 1); STEP(6, t0 + 2); STEP(7, t0 + 3);
        BATCH(0, t0 + 8);
        asm volatile("s_waitcnt vmcnt(12)" ::: "memory");
        STEP(8, t0 + 4); STEP(9, t0 + 5); STEP(10, t0 + 6); STEP(11, t0 + 7);
        BATCH(4, t0 + 12);
        asm volatile("s_waitcnt vmcnt(12)" ::: "memory");
        STEP(0, t0 + 8); STEP(1, t0 + 9); STEP(2, t0 + 10); STEP(3, t0 + 11);
        BATCH(8, t0 + 16);
    }
}

extern "C" void kernel_launch(void* const* d_in, const int* in_sizes, int n_in,
                              void* d_out, int out_size, void* d_ws, size_t ws_size,
                              hipStream_t stream) {
    const float* x = (const float*)d_in[0];      // [256,1,512,512] f32
    const float* kern = (const float*)d_in[1];   // [5,5] f32
    float* out = (float*)d_out;                  // [256,1,512,512] f32

    conv_li_kernel<<<dim3(1024), dim3(64), 0, stream>>>(x, kern, out);
}

// Round 11
// 124.736 us; speedup vs baseline: 1.3044x; 1.0227x over previous
//
#include <hip/hip_runtime.h>

#define T_STEPS 256
#define IMG 512
#define HW (IMG * IMG)
#define TW 32
#define TH 8
#define HTW 40                 // dwords per halo row (cols -4..35) = 10 chunks
#define HTH 12                 // halo rows -2..9
#define NCHK 120               // real 16B chunks per frame
#define BUF_DW 512             // 128 chunks (8 dummy) * 4 dwords per frame buffer
#define NBUF 8                 // ring of 8 frame buffers = 16 KiB LDS

// Zero page for fully-OOB chunks/rows (device global: never written, stays 0).
__device__ __align__(16) float g_zeropage[8] = {0, 0, 0, 0, 0, 0, 0, 0};

typedef const __attribute__((address_space(1))) unsigned int* gptr_t;
typedef __attribute__((address_space(3))) unsigned int* lptr_t;
typedef float vf4 __attribute__((ext_vector_type(4)));

// out[t] = 0.8*out[t-1] + conv(x)[t-1]; out[0]=0 — conv and LI scan commute.
// Single-wave blocks, no barriers. Window = lo/hi chunks from LDS (2 aligned
// ds_read_b128) + MIDDLE chunk via global_load_dwordx4 (L2-hit, prefetched
// 1 step ahead, M0/M1 double buffer) -> DS pipe load cut 15->10 b128/step.
// Ring-8 LDS frames, counted vmcnt per 4-step group; compiler memory
// barriers pin each glds BATCH last-in-region so counts are exact.
__launch_bounds__(64)
__global__ void conv_li_kernel(const float* __restrict__ x,
                               const float* __restrict__ kern,
                               float* __restrict__ out) {
    __shared__ __align__(16) float lds[NBUF][BUF_DW];
    const int tid = threadIdx.x;
    const int bid = blockIdx.x;
    // 1024 blocks over 8 XCDs (bijective): halo sharing stays per-XCD L2.
    const int vbid = (bid & 7) * 128 + (bid >> 3);
    const int bx = vbid & 15;      // 16 tiles across
    const int by = vbid >> 4;      // 64 tile rows

    // 5x5 kernel -> wave-uniform (SGPR) weights.
    float kw[25];
#pragma unroll
    for (int i = 0; i < 25; ++i)
        kw[i] = __int_as_float(__builtin_amdgcn_readfirstlane(__float_as_int(kern[i])));

    // DMA source chunks (identical to R7 champion).
    const float* srcA; const float* srcB; bool okA, okB;
    {
        int c = tid;
        int row = c / 10, cc = c - row * 10;
        int gy = by * TH + row - 2, gx = bx * TW + cc * 4 - 4;
        okA = (gy >= 0) && (gy < IMG) && (gx >= 0) && (gx <= IMG - 4);
        srcA = x + (size_t)(okA ? gy : 0) * IMG + (okA ? gx : 0);
        c = tid + 64;
        row = c / 10; cc = c - row * 10;
        gy = by * TH + row - 2; gx = bx * TW + cc * 4 - 4;
        okB = (c < NCHK) && (gy >= 0) && (gy < IMG) && (gx >= 0) && (gx <= IMG - 4);
        srcB = x + (size_t)(okB ? gy : 0) * IMG + (okB ? gx : 0);
    }

    auto GLDS = [&](int bi, int tf) {
        const float* pA = okA ? srcA + (size_t)tf * HW : g_zeropage;
        const float* pB = okB ? srcB + (size_t)tf * HW : g_zeropage;
        __builtin_amdgcn_global_load_lds((gptr_t)pA, (lptr_t)&lds[bi][0], 16, 0, 0);
        __builtin_amdgcn_global_load_lds((gptr_t)pB, (lptr_t)&lds[bi][256], 16, 0, 0);
    };
    auto BATCH = [&](int bufbase, int f0) {   // 4 frames = 8 glds
        asm volatile("" ::: "memory");        // pin: nothing sinks below into batch
#pragma unroll
        for (int j = 0; j < 4; ++j) {
            int tf = f0 + j; if (tf > T_STEPS - 1) tf = T_STEPS - 1;
            GLDS(bufbase + j, tf);
        }
    };

    const int q = tid & 7;         // col-quad (4 out cols)
    const int rr = tid >> 3;       // out row within tile
    const size_t obase = (size_t)(by * TH + rr) * IMG + bx * TW + q * 4;

    // Middle-chunk prefetch pointers: row gy = by*8+rr+dy-2, cols bx*32+4q..+3
    // (16B-aligned global; always in-image horizontally; OOB rows -> zeropage).
    const float* rowmid[5]; bool rowok[5];
#pragma unroll
    for (int dy = 0; dy < 5; ++dy) {
        int gy = by * TH + rr + dy - 2;
        rowok[dy] = (gy >= 0) && (gy < IMG);
        rowmid[dy] = rowok[dy] ? (x + (size_t)gy * IMG + bx * TW + q * 4)
                               : (const float*)g_zeropage;
    }

    vf4 M0[5], M1[5];
    auto PF = [&](vf4* M, int tf) {           // 5 global_load_dwordx4 (L2 hits)
#pragma unroll
        for (int dy = 0; dy < 5; ++dy) {
            size_t off = rowok[dy] ? (size_t)tf * HW : 0;
            M[dy] = *(const vf4*)(rowmid[dy] + off);
        }
    };

    vf4 st = {0.f, 0.f, 0.f, 0.f};

    auto STEP = [&](int bi, int t, const vf4* M) {
        float ax = 0.f, ay = 0.f, az = 0.f, aw = 0.f;
        const float* Bp = &lds[bi][rr * HTW + q * 4];
#pragma unroll
        for (int dy = 0; dy < 5; ++dy) {
            const float* L = Bp + dy * HTW;
            vf4 lo = *(const vf4*)(L);        // dwords 4q..4q+3   (use .z,.w)
            vf4 hi = *(const vf4*)(L + 8);    // dwords 4q+8..+11  (use .x,.y)
            vf4 md = M[dy];                   // dwords 4q+4..+7   (all)
            const float d2 = lo.z, d3 = lo.w, d4 = md.x, d5 = md.y;
            const float d6 = md.z, d7 = md.w, d8 = hi.x, d9 = hi.y;
            const float k0 = kw[dy * 5 + 0], k1 = kw[dy * 5 + 1], k2 = kw[dy * 5 + 2];
            const float k3 = kw[dy * 5 + 3], k4 = kw[dy * 5 + 4];
            ax = fmaf(k0, d2, ax); ax = fmaf(k1, d3, ax); ax = fmaf(k2, d4, ax);
            ax = fmaf(k3, d5, ax); ax = fmaf(k4, d6, ax);
            ay = fmaf(k0, d3, ay); ay = fmaf(k1, d4, ay); ay = fmaf(k2, d5, ay);
            ay = fmaf(k3, d6, ay); ay = fmaf(k4, d7, ay);
            az = fmaf(k0, d4, az); az = fmaf(k1, d5, az); az = fmaf(k2, d6, az);
            az = fmaf(k3, d7, az); az = fmaf(k4, d8, az);
            aw = fmaf(k0, d5, aw); aw = fmaf(k1, d6, aw); aw = fmaf(k2, d7, aw);
            aw = fmaf(k3, d8, aw); aw = fmaf(k4, d9, aw);
        }
        vf4 s = st;
        __builtin_nontemporal_store(s, (vf4*)(out + (size_t)t * HW + obase));
        st.x = st.x - 0.2f * st.x + ax;      // S_t = 0.8*S_{t-1} + y[t]
        st.y = st.y - 0.2f * st.y + ay;
        st.z = st.z - 0.2f * st.z + az;
        st.w = st.w - 0.2f * st.w + aw;
    };

    // Group of 4 steps; M phases static: even step uses M0, odd uses M1.
#define GROUP4(BB, T0)                                        \
    do {                                                      \
        PF(M1, (T0) + 1); STEP((BB) + 0, (T0) + 0, M0);       \
        PF(M0, (T0) + 2); STEP((BB) + 1, (T0) + 1, M1);       \
        PF(M1, (T0) + 3); STEP((BB) + 2, (T0) + 2, M0);       \
        int tn_ = (T0) + 4; if (tn_ > 255) tn_ = 255;         \
        PF(M0, tn_);      STEP((BB) + 3, (T0) + 3, M1);       \
    } while (0)

    // Prologue: B0 (frames 0-3 -> bufs 0-3), B1 (4-7 -> bufs 4-7), PF M0(t0).
    BATCH(0, 0);
    BATCH(4, 4);
    PF(M0, 0);

    // g0: ops newer than B0 = B1(8) + PF(5) = 13.
    asm volatile("s_waitcnt vmcnt(13)" ::: "memory");
    GROUP4(0, 0);
    BATCH(0, 8);
    // g1: newer than B1 = PFpro(5) + g0[20 PF + 4 st](24) + B2(8) = 37.
    asm volatile("s_waitcnt vmcnt(37)" ::: "memory");
    GROUP4(4, 4);
    BATCH(4, 12);
    // g>=2 steady: newer than target batch = prev group [24] + next batch [8] = 32.
#pragma clang loop unroll(disable)
    for (int g = 2; g < 64; ++g) {
        const int bb = (g & 1) * 4;
        const int t0 = g * 4;
        asm volatile("s_waitcnt vmcnt(32)" ::: "memory");
        GROUP4(bb, t0);
        BATCH(bb, t0 + 8);
    }
#undef GROUP4
}

extern "C" void kernel_launch(void* const* d_in, const int* in_sizes, int n_in,
                              void* d_out, int out_size, void* d_ws, size_t ws_size,
                              hipStream_t stream) {
    const float* x = (const float*)d_in[0];      // [256,1,512,512] f32
    const float* kern = (const float*)d_in[1];   // [5,5] f32
    float* out = (float*)d_out;                  // [256,1,512,512] f32

    conv_li_kernel<<<dim3(1024), dim3(64), 0, stream>>>(x, kern, out);
}

// Round 12
// 97.113 us; speedup vs baseline: 1.6754x; 1.2845x over previous
//
#include <hip/hip_runtime.h>

#define T_STEPS 256
#define IMG 512
#define HW (IMG * IMG)
#define TW 32
#define TH 8
#define HTW 40                 // dwords per halo row (cols -4..35) = 10 chunks
#define HTH 12                 // halo rows -2..9
#define NCHK 120               // real 16B chunks per frame
#define BUF_DW 512             // 128 chunks (8 dummy) * 4 dwords per frame buffer
#define NBUF 12                // ring of 12 frame buffers = 24 KiB LDS

// Zero page for fully-OOB halo chunks (device global: never written, stays 0).
__device__ __align__(16) float g_zeropage[8] = {0, 0, 0, 0, 0, 0, 0, 0};

typedef const __attribute__((address_space(1))) unsigned int* gptr_t;
typedef __attribute__((address_space(3))) unsigned int* lptr_t;
typedef float vf4 __attribute__((ext_vector_type(4)));
typedef float vf2 __attribute__((ext_vector_type(2)));

// out[t] = 0.8*out[t-1] + conv(x)[t-1]; out[0]=0 — conv and LI scan commute.
// R7 champion memory structure (single-wave blocks, no barriers, glds DMA,
// ring-12, counted vmcnt never touching stores, 3x contiguous ds_read_b128).
// NEW: conv arithmetic in packed fp32 (v_pk_fma_f32) — 12 pk_fma/row on the
// naturally pair-aligned dwords (d2,d3)(d4,d5)(d6,d7)(d8,d9) instead of 20
// scalar FMAs -> attacks the measured VALU-issue bound (1 wave/SIMD, ~86%).
__launch_bounds__(64)
__global__ void conv_li_kernel(const float* __restrict__ x,
                               const float* __restrict__ kern,
                               float* __restrict__ out) {
    __shared__ __align__(16) float lds[NBUF][BUF_DW];
    const int tid = threadIdx.x;
    const int bid = blockIdx.x;
    // 1024 blocks over 8 XCDs (bijective): vertical halo sharing stays per-XCD L2.
    const int vbid = (bid & 7) * 128 + (bid >> 3);
    const int bx = vbid & 15;      // 16 tiles across
    const int by = vbid >> 4;      // 64 tile rows

    // 5x5 kernel -> wave-uniform weights, as pair constants for pk_fma.
    float kw[25];
#pragma unroll
    for (int i = 0; i < 25; ++i)
        kw[i] = __int_as_float(__builtin_amdgcn_readfirstlane(__float_as_int(kern[i])));

    // DMA source chunks (identical to R7 champion).
    const float* srcA; const float* srcB; bool okA, okB;
    {
        int c = tid;
        int row = c / 10, cc = c - row * 10;
        int gy = by * TH + row - 2, gx = bx * TW + cc * 4 - 4;
        okA = (gy >= 0) && (gy < IMG) && (gx >= 0) && (gx <= IMG - 4);
        srcA = x + (size_t)(okA ? gy : 0) * IMG + (okA ? gx : 0);
        c = tid + 64;
        row = c / 10; cc = c - row * 10;
        gy = by * TH + row - 2; gx = bx * TW + cc * 4 - 4;
        okB = (c < NCHK) && (gy >= 0) && (gy < IMG) && (gx >= 0) && (gx <= IMG - 4);
        srcB = x + (size_t)(okB ? gy : 0) * IMG + (okB ? gx : 0);
    }

    auto GLDS = [&](int bi, int tf) {
        const float* pA = okA ? srcA + (size_t)tf * HW : g_zeropage;
        const float* pB = okB ? srcB + (size_t)tf * HW : g_zeropage;
        __builtin_amdgcn_global_load_lds((gptr_t)pA, (lptr_t)&lds[bi][0], 16, 0, 0);
        __builtin_amdgcn_global_load_lds((gptr_t)pB, (lptr_t)&lds[bi][256], 16, 0, 0);
    };
    auto BATCH = [&](int bufbase, int f0) {   // 4 frames = 8 glds, issued in order
#pragma unroll
        for (int j = 0; j < 4; ++j) {
            int tf = f0 + j; if (tf > T_STEPS - 1) tf = T_STEPS - 1;
            GLDS(bufbase + j, tf);
        }
    };

    const int q = tid & 7;         // col-quad (4 out cols)
    const int rr = tid >> 3;       // out row within tile
    const size_t obase = (size_t)(by * TH + rr) * IMG + bx * TW + q * 4;

    vf2 stA = {0.f, 0.f}, stB = {0.f, 0.f};   // state for (x,y) and (z,w)

    auto STEP = [&](int bi, int t) {
        vf2 A0 = {0.f, 0.f}, A1 = {0.f, 0.f}, A2 = {0.f, 0.f}, A3 = {0.f, 0.f};
        const float* Bp = &lds[bi][rr * HTW + q * 4];
#pragma unroll
        for (int dy = 0; dy < 5; ++dy) {
            const float* L = Bp + dy * HTW;
            vf4 c0 = *(const vf4*)(L);        // d0..d3 (use d2,d3)
            vf4 c1 = *(const vf4*)(L + 4);    // d4..d7
            vf4 c2 = *(const vf4*)(L + 8);    // d8..d11 (use d8,d9)
            vf2 P0 = {c0.z, c0.w};            // (d2,d3) — aligned pair
            vf2 P1 = {c1.x, c1.y};            // (d4,d5)
            vf2 P2 = {c1.z, c1.w};            // (d6,d7)
            vf2 P3 = {c2.x, c2.y};            // (d8,d9)
            const float k0 = kw[dy * 5 + 0], k1 = kw[dy * 5 + 1], k2 = kw[dy * 5 + 2];
            const float k3 = kw[dy * 5 + 3], k4 = kw[dy * 5 + 4];
            const vf2 K01 = {k0, k1}, K23 = {k2, k3}, K40 = {k4, 0.f};
            const vf2 K0h = {0.f, k0}, K12 = {k1, k2}, K34 = {k3, k4};
            // out x: k·(d2..d6)   out y: k·(d3..d7)
            A0 = __builtin_elementwise_fma(K01, P0, A0);
            A0 = __builtin_elementwise_fma(K23, P1, A0);
            A0 = __builtin_elementwise_fma(K40, P2, A0);
            A1 = __builtin_elementwise_fma(K0h, P0, A1);
            A1 = __builtin_elementwise_fma(K12, P1, A1);
            A1 = __builtin_elementwise_fma(K34, P2, A1);
            // out z: k·(d4..d8)   out w: k·(d5..d9)
            A2 = __builtin_elementwise_fma(K01, P1, A2);
            A2 = __builtin_elementwise_fma(K23, P2, A2);
            A2 = __builtin_elementwise_fma(K40, P3, A2);
            A3 = __builtin_elementwise_fma(K0h, P1, A3);
            A3 = __builtin_elementwise_fma(K12, P2, A3);
            A3 = __builtin_elementwise_fma(K34, P3, A3);
        }
        vf4 s = {stA.x, stA.y, stB.x, stB.y};
        __builtin_nontemporal_store(s, (vf4*)(out + (size_t)t * HW + obase));
        // S_t = 0.8*S + y[t]; horizontal pair-sum folded into packed update.
        vf2 accA = {A0.x + A0.y, A1.x + A1.y};
        vf2 accB = {A2.x + A2.y, A3.x + A3.y};
        const vf2 m02 = {-0.2f, -0.2f};
        stA = __builtin_elementwise_fma(m02, stA, stA) + accA;
        stB = __builtin_elementwise_fma(m02, stB, stB) + accB;
    };

    // Prologue: frames 0..7 in flight (16 glds).
    BATCH(0, 0);
    BATCH(4, 4);

    // Group 0 (frames 0..3): outstanding 16, need oldest 8 -> vmcnt(8).
    asm volatile("s_waitcnt vmcnt(8)" ::: "memory");
    STEP(0, 0); STEP(1, 1); STEP(2, 2); STEP(3, 3);
    BATCH(8, 8);

    // Steady state: at group top, outstanding = batch(this:8) + stores(4) +
    // batch(next:8) = 20; waited batch is oldest -> vmcnt(12) never touches
    // stores. 21 super-groups x 12 steps = t 4..255.
#pragma clang loop unroll(disable)
    for (int sg = 0; sg < 21; ++sg) {
        const int t0 = 4 + sg * 12;
        asm volatile("s_waitcnt vmcnt(12)" ::: "memory");
        STEP(4, t0 + 0); STEP(5, t0 + 1); STEP(6, t0 + 2); STEP(7, t0 + 3);
        BATCH(0, t0 + 8);
        asm volatile("s_waitcnt vmcnt(12)" ::: "memory");
        STEP(8, t0 + 4); STEP(9, t0 + 5); STEP(10, t0 + 6); STEP(11, t0 + 7);
        BATCH(4, t0 + 12);
        asm volatile("s_waitcnt vmcnt(12)" ::: "memory");
        STEP(0, t0 + 8); STEP(1, t0 + 9); STEP(2, t0 + 10); STEP(3, t0 + 11);
        BATCH(8, t0 + 16);
    }
}

extern "C" void kernel_launch(void* const* d_in, const int* in_sizes, int n_in,
                              void* d_out, int out_size, void* d_ws, size_t ws_size,
                              hipStream_t stream) {
    const float* x = (const float*)d_in[0];      // [256,1,512,512] f32
    const float* kern = (const float*)d_in[1];   // [5,5] f32
    float* out = (float*)d_out;                  // [256,1,512,512] f32

    conv_li_kernel<<<dim3(1024), dim3(64), 0, stream>>>(x, kern, out);
}